// Round 5
// baseline (15120.622 us; speedup 1.0000x reference)
//
#include <hip/hip_runtime.h>
#include <hip/hip_bf16.h>

// LSTM B=64, T=512, I=512, H=1024.
// Persistent kernel, 64 WGs x 1024 thr, 1 WG/CU.
// U slice (64x1024 bf16, XOR-swizzled) resident in LDS for all 512 steps.
// h exchange: per-lane 16B inline-asm global_load_dwordx4 sc1 (device-coherent,
// pipelined with counted vmcnt) -- replaces 16 serialized atomic loads/thread.
// x/W fragments: normal cached per-lane 16B loads, before the flag wait.
// 3 barriers/step. Per-WG flag lines; 3 rotating h buffers.
// Spin bound tightened to 2^16 so a desync can never wedge the container.

typedef __attribute__((ext_vector_type(8))) short bf16x8;
typedef __attribute__((ext_vector_type(4))) float f32x4;
typedef __attribute__((ext_vector_type(4))) unsigned int u32x4;
typedef unsigned int uint32;
typedef unsigned long long u64;

static __device__ __forceinline__ unsigned short f2bf(float f) {
    union { float f; unsigned int u; } v; v.f = f;
    unsigned int r = v.u + 0x7fffu + ((v.u >> 16) & 1u);  // RNE
    return (unsigned short)(r >> 16);
}

#define NB   64
#define NT   512
#define NI   512
#define NH   1024
#define NWG  64

// ================= fast path =================

// prep: W f32->bf16 [4][1024][512]; x transpose+convert -> xT[t][b][i] bf16;
// zero flag region (0xAA poison must not look like a set flag).
__global__ void prep3(const float* __restrict__ x,
                      const float* __restrict__ Wi, const float* __restrict__ Wf,
                      const float* __restrict__ Wc, const float* __restrict__ Wo,
                      unsigned short* __restrict__ Wb, unsigned short* __restrict__ xTb,
                      int* __restrict__ flags)
{
    const int NW = 4 * NH * NI;          // 2097152
    const int NX = NB * NT * NI;         // 16777216
    const int NF = NT * 1024;            // 524288 ints (flag lines, 64B/WG/step)
    const int total = NW + NX + NF;
    for (int idx = blockIdx.x * blockDim.x + threadIdx.x; idx < total;
         idx += gridDim.x * blockDim.x) {
        if (idx < NW) {
            int g = idx >> 19;
            int off = idx & 524287;
            const float* W = (g == 0) ? Wi : (g == 1) ? Wf : (g == 2) ? Wc : Wo;
            Wb[idx] = f2bf(W[off]);
        } else if (idx < NW + NX) {
            int e = idx - NW;
            int b = e >> 18;              // T*I = 262144
            int r = e & 262143;
            int t = r >> 9;
            int i = r & 511;
            xTb[((size_t)t * NB + b) * NI + i] = f2bf(x[e]);
        } else {
            flags[idx - NW - NX] = 0;
        }
    }
}

// issue 4 h-fragment loads (device-coherent, 16B each, literal offsets)
#define HLOAD4(V0, V1, V2, V3, O0, O1, O2, O3)                                  \
    asm volatile("global_load_dwordx4 %0, %4, off offset:" O0 " sc1\n\t"        \
                 "global_load_dwordx4 %1, %4, off offset:" O1 " sc1\n\t"        \
                 "global_load_dwordx4 %2, %4, off offset:" O2 " sc1\n\t"        \
                 "global_load_dwordx4 %3, %4, off offset:" O3 " sc1"            \
                 : "=v"(V0), "=v"(V1), "=v"(V2), "=v"(V3)                       \
                 : "v"(hP) : "memory")

#define VMWAIT(N)                                                               \
    do { asm volatile("s_waitcnt vmcnt(" #N ")" ::: "memory");                  \
         __builtin_amdgcn_sched_barrier(0); } while (0)

// consume 4 fragments (one 128-k chunk): MFMA against U in LDS
#define HMFMA4(ACC, V0, V1, V2, V3, KB)                                         \
    do {                                                                        \
        bf16x8 u_0 = *(const bf16x8*)(Us + ubase + ((((KB) + 0   + kg) * 2) ^ (rm << 4))); \
        ACC = __builtin_amdgcn_mfma_f32_16x16x32_bf16(__builtin_bit_cast(bf16x8, V0), u_0, ACC, 0, 0, 0); \
        bf16x8 u_1 = *(const bf16x8*)(Us + ubase + ((((KB) + 32  + kg) * 2) ^ (rm << 4))); \
        ACC = __builtin_amdgcn_mfma_f32_16x16x32_bf16(__builtin_bit_cast(bf16x8, V1), u_1, ACC, 0, 0, 0); \
        bf16x8 u_2 = *(const bf16x8*)(Us + ubase + ((((KB) + 64  + kg) * 2) ^ (rm << 4))); \
        ACC = __builtin_amdgcn_mfma_f32_16x16x32_bf16(__builtin_bit_cast(bf16x8, V2), u_2, ACC, 0, 0, 0); \
        bf16x8 u_3 = *(const bf16x8*)(Us + ubase + ((((KB) + 96  + kg) * 2) ^ (rm << 4))); \
        ACC = __builtin_amdgcn_mfma_f32_16x16x32_bf16(__builtin_bit_cast(bf16x8, V3), u_3, ACC, 0, 0, 0); \
    } while (0)

__global__ __launch_bounds__(1024) void lstm_persist4(
    const float* __restrict__ Ui, const float* __restrict__ Uf,
    const float* __restrict__ Uc, const float* __restrict__ Uo,
    const float* __restrict__ b_i, const float* __restrict__ b_f,
    const float* __restrict__ b_c, const float* __restrict__ b_o,
    const unsigned short* __restrict__ Wb, const unsigned short* __restrict__ xT,
    unsigned short* __restrict__ hb,      // 3 rotating [64][1024] bf16 buffers
    int* __restrict__ flags,              // [NT][64 wg][16 ints] (64B lines)
    float* __restrict__ out, float* __restrict__ hn_arr, float* __restrict__ cn_arr)
{
    __shared__ __align__(16) unsigned char smem[147456];   // 128K U + 16K gacc
    unsigned char* Us = smem;                    // 64 rows x 2048B swizzled U slice
    float* gacc = (float*)(smem + 131072);       // [4][64][16] f32

    const int tid  = threadIdx.x;
    const int lane = tid & 63;
    const int wv   = tid >> 6;      // 0..15
    const int g    = wv & 3;        // gate
    const int mt   = wv >> 2;       // b-tile (16 rows)
    const int rm   = lane & 15;
    const int kg   = (lane >> 4) * 8;
    const int wg   = blockIdx.x;
    const int u0   = wg * 16;

    // ---- prologue: fill U LDS slice (f32 -> bf16, XOR-swizzled rows) ----
    for (int i = 0; i < 8; ++i) {
        int unit = i * 1024 + tid;          // 16B units: 64 rows x 128
        int row  = unit >> 7;
        int k0   = (unit & 127) * 8;
        int gg   = row >> 4;
        const float* src = (gg == 0 ? Ui : gg == 1 ? Uf : gg == 2 ? Uc : Uo)
                           + (size_t)(u0 + (row & 15)) * NH + k0;
        bf16x8 v;
        #pragma unroll
        for (int j = 0; j < 8; ++j) v[j] = (short)f2bf(src[j]);
        *(bf16x8*)(Us + row * 2048 + ((k0 * 2) ^ ((row & 15) << 4))) = v;
    }

    const int bl = tid >> 4, ul = tid & 15;
    const float rbi = b_i[u0 + ul], rbf = b_f[u0 + ul];
    const float rbc = b_c[u0 + ul], rbo = b_o[u0 + ul];
    float creg = 0.f;

    const int ubase = (g * 16 + rm) * 2048;
    const size_t wrow = ((size_t)(g * NH + u0 + rm)) * NI;
    const unsigned short* wp = Wb + wrow + kg;

    __syncthreads();

    for (int t = 0; t < NT; ++t) {
        f32x4 accx = {0.f, 0.f, 0.f, 0.f};
        f32x4 acc0 = {0.f, 0.f, 0.f, 0.f};
        f32x4 acc1 = {0.f, 0.f, 0.f, 0.f};

        // ===== X part (no h dependency, cached loads, before the flag wait) =====
        {
            const unsigned short* xp = xT + ((size_t)t * NB + mt * 16 + rm) * NI + kg;
            #pragma unroll
            for (int c = 0; c < 4; ++c) {
                #pragma unroll
                for (int kk = 0; kk < 4; ++kk) {
                    bf16x8 ax = *(const bf16x8*)(xp + c * 128 + kk * 32);
                    bf16x8 bw = *(const bf16x8*)(wp + c * 128 + kk * 32);
                    accx = __builtin_amdgcn_mfma_f32_16x16x32_bf16(ax, bw, accx, 0, 0, 0);
                }
            }
        }

        // ===== H part =====
        if (t > 0) {
            // wait for all producers of step t-1 (64 parallel flag-line reads)
            if (wv == 0) {
                const int* fp = flags + (size_t)(t - 1) * 1024 + lane * 16;
                int spins = 0;
                while (__hip_atomic_load(fp, __ATOMIC_RELAXED,
                                         __HIP_MEMORY_SCOPE_AGENT) == 0 &&
                       spins < (1 << 16)) {
                    __builtin_amdgcn_s_sleep(1);
                    ++spins;
                }
            }
            __syncthreads();   // B2 (drains all outstanding VMEM -> counts valid)

            const char* hP = (const char*)hb + ((size_t)((t - 1) % 3) << 17)
                             + ((size_t)(mt * 16 + rm) << 11) + (kg << 1);
            u32x4 fa0, fa1, fa2, fa3, fb0, fb1, fb2, fb3;
            u32x4 fc0, fc1, fc2, fc3, fd0, fd1, fd2, fd3;
            // prologue: chunks 0..3 in flight (16 loads)
            HLOAD4(fa0, fa1, fa2, fa3, "0",   "64",  "128", "192");
            HLOAD4(fb0, fb1, fb2, fb3, "256", "320", "384", "448");
            HLOAD4(fc0, fc1, fc2, fc3, "512", "576", "640", "704");
            HLOAD4(fd0, fd1, fd2, fd3, "768", "832", "896", "960");
            // steady state: wait chunk, consume, issue chunk+4
            VMWAIT(12); HMFMA4(acc0, fa0, fa1, fa2, fa3, 0);
            HLOAD4(fa0, fa1, fa2, fa3, "1024", "1088", "1152", "1216");
            VMWAIT(12); HMFMA4(acc1, fb0, fb1, fb2, fb3, 128);
            HLOAD4(fb0, fb1, fb2, fb3, "1280", "1344", "1408", "1472");
            VMWAIT(12); HMFMA4(acc0, fc0, fc1, fc2, fc3, 256);
            HLOAD4(fc0, fc1, fc2, fc3, "1536", "1600", "1664", "1728");
            VMWAIT(12); HMFMA4(acc1, fd0, fd1, fd2, fd3, 384);
            HLOAD4(fd0, fd1, fd2, fd3, "1792", "1856", "1920", "1984");
            VMWAIT(12); HMFMA4(acc0, fa0, fa1, fa2, fa3, 512);
            VMWAIT(8);  HMFMA4(acc1, fb0, fb1, fb2, fb3, 640);
            VMWAIT(4);  HMFMA4(acc0, fc0, fc1, fc2, fc3, 768);
            VMWAIT(0);  HMFMA4(acc1, fd0, fd1, fd2, fd3, 896);
        }

        // ======= gate exchange (C/D layout: col=lane&15, row=(lane>>4)*4+r) =======
        #pragma unroll
        for (int r = 0; r < 4; ++r) {
            const int brow = mt * 16 + (lane >> 4) * 4 + r;
            gacc[(g * 64 + brow) * 16 + rm] = accx[r] + acc0[r] + acc1[r];
        }
        __syncthreads();   // B1

        // ======= pointwise: thread owns (b=bl, u=u0+ul); c-state in register =======
        float hn2, cn2;
        {
            float pi = gacc[(0 * 64 + bl) * 16 + ul] + rbi;
            float pf = gacc[(1 * 64 + bl) * 16 + ul] + rbf;
            float pg = gacc[(2 * 64 + bl) * 16 + ul] + rbc;
            float po = gacc[(3 * 64 + bl) * 16 + ul] + rbo;
            float ig  = 1.f / (1.f + __expf(-pi));
            float fg  = 1.f / (1.f + __expf(-pf));
            float gg2 = tanhf(pg);
            float og  = 1.f / (1.f + __expf(-po));
            cn2 = fg * creg + ig * gg2;
            hn2 = og * tanhf(cn2);
            creg = cn2;

            // pack 4 consecutive u into one u64, device-scope store to rotating buf
            unsigned short h16 = f2bf(hn2);
            uint32 lo = (uint32)h16 |
                        ((((uint32)__shfl_down((int)h16, 1, 64)) & 0xffffu) << 16);
            u64 p4 = (u64)lo | ((u64)(uint32)__shfl_down((int)lo, 2, 64) << 32);
            if ((ul & 3) == 0) {
                u64* hd = (u64*)hb + (size_t)(t % 3) * 16384
                          + (size_t)bl * 256 + (size_t)((u0 + ul) >> 2);
                __hip_atomic_store(hd, p4, __ATOMIC_RELAXED,
                                   __HIP_MEMORY_SCOPE_AGENT);
            }
        }

        // B_f: drains h stores (syncthreads implies vmcnt(0)); then flag
        __syncthreads();
        if (tid == 0)
            __hip_atomic_store(flags + (size_t)t * 1024 + wg * 16, 1,
                               __ATOMIC_RELAXED, __HIP_MEMORY_SCOPE_AGENT);

        // out store after the flag (off the inter-WG critical path)
        out[((size_t)bl * NT + t) * NH + u0 + ul] = hn2;
        if (t == NT - 1) {
            hn_arr[(size_t)bl * NH + u0 + ul] = hn2;
            cn_arr[(size_t)bl * NH + u0 + ul] = cn2;
        }
    }
}

// ================= round-1 fallback (proven) =================

__global__ void lstm_prep(const float* __restrict__ Ui, const float* __restrict__ Uf,
                          const float* __restrict__ Uc, const float* __restrict__ Uo,
                          const float* __restrict__ Wi, const float* __restrict__ Wf,
                          const float* __restrict__ Wc, const float* __restrict__ Wo,
                          unsigned short* __restrict__ Ub, unsigned short* __restrict__ Wb,
                          unsigned short* __restrict__ hb0, float* __restrict__ c_state)
{
    const int NU = 4 * NH * NH;
    const int NW = 4 * NH * NI;
    const int NS = NB * NH;
    const int total = NU + NW + NS + NS;
    for (int idx = blockIdx.x * blockDim.x + threadIdx.x; idx < total;
         idx += gridDim.x * blockDim.x) {
        if (idx < NU) {
            int g = idx >> 20;
            int off = idx & (NH * NH - 1);
            const float* U = (g == 0) ? Ui : (g == 1) ? Uf : (g == 2) ? Uc : Uo;
            Ub[idx] = f2bf(U[off]);
        } else if (idx < NU + NW) {
            int j = idx - NU;
            int g = j >> 19;
            int off = j & (NH * NI - 1);
            const float* W = (g == 0) ? Wi : (g == 1) ? Wf : (g == 2) ? Wc : Wo;
            Wb[j] = f2bf(W[off]);
        } else if (idx < NU + NW + NS) {
            hb0[idx - NU - NW] = 0;
        } else {
            c_state[idx - NU - NW - NS] = 0.0f;
        }
    }
}

__global__ __launch_bounds__(256) void lstm_step(
    const float* __restrict__ x,
    const unsigned short* __restrict__ Ub,
    const unsigned short* __restrict__ Wb,
    const unsigned short* __restrict__ hb_in,
    unsigned short* __restrict__ hb_out,
    const float* __restrict__ bi, const float* __restrict__ bff,
    const float* __restrict__ bc, const float* __restrict__ bo,
    float* __restrict__ out, float* __restrict__ c_state,
    float* __restrict__ hn_out, int t)
{
    __shared__ float gacc[4][32][16];
    const int lane = threadIdx.x & 63;
    const int g    = threadIdx.x >> 6;
    const int u0   = (blockIdx.x >> 1) * 16;
    const int b0   = (blockIdx.x & 1) * 32;
    const int rm   = lane & 15;
    const int kg   = (lane >> 4) * 8;

    f32x4 acc0 = {0.f, 0.f, 0.f, 0.f};
    f32x4 acc1 = {0.f, 0.f, 0.f, 0.f};

    const unsigned short* Ug  = Ub + (size_t)g * (NH * NH) + (size_t)(u0 + rm) * NH;
    const unsigned short* h0p = hb_in + (size_t)(b0 + rm) * NH;
    const unsigned short* h1p = hb_in + (size_t)(b0 + 16 + rm) * NH;
    #pragma unroll 4
    for (int k0 = 0; k0 < NH; k0 += 32) {
        bf16x8 bfrag = *(const bf16x8*)(Ug + k0 + kg);
        bf16x8 a0 = *(const bf16x8*)(h0p + k0 + kg);
        bf16x8 a1 = *(const bf16x8*)(h1p + k0 + kg);
        acc0 = __builtin_amdgcn_mfma_f32_16x16x32_bf16(a0, bfrag, acc0, 0, 0, 0);
        acc1 = __builtin_amdgcn_mfma_f32_16x16x32_bf16(a1, bfrag, acc1, 0, 0, 0);
    }
    const unsigned short* Wg  = Wb + (size_t)g * (NH * NI) + (size_t)(u0 + rm) * NI;
    const float* x0p = x + ((size_t)(b0 + rm) * NT + t) * NI;
    const float* x1p = x + ((size_t)(b0 + 16 + rm) * NT + t) * NI;
    #pragma unroll 2
    for (int k0 = 0; k0 < NI; k0 += 32) {
        bf16x8 bfrag = *(const bf16x8*)(Wg + k0 + kg);
        f32x4 lo0 = *(const f32x4*)(x0p + k0 + kg);
        f32x4 hi0 = *(const f32x4*)(x0p + k0 + kg + 4);
        f32x4 lo1 = *(const f32x4*)(x1p + k0 + kg);
        f32x4 hi1 = *(const f32x4*)(x1p + k0 + kg + 4);
        bf16x8 a0, a1;
        #pragma unroll
        for (int j = 0; j < 4; j++) {
            a0[j]     = (short)f2bf(lo0[j]);
            a0[j + 4] = (short)f2bf(hi0[j]);
            a1[j]     = (short)f2bf(lo1[j]);
            a1[j + 4] = (short)f2bf(hi1[j]);
        }
        acc0 = __builtin_amdgcn_mfma_f32_16x16x32_bf16(a0, bfrag, acc0, 0, 0, 0);
        acc1 = __builtin_amdgcn_mfma_f32_16x16x32_bf16(a1, bfrag, acc1, 0, 0, 0);
    }
    const int row4 = (lane >> 4) * 4;
    #pragma unroll
    for (int r = 0; r < 4; r++) {
        gacc[g][row4 + r][rm]      = acc0[r];
        gacc[g][16 + row4 + r][rm] = acc1[r];
    }
    __syncthreads();
    for (int p = threadIdx.x; p < 512; p += 256) {
        int bl = p >> 4, ul = p & 15;
        int b = b0 + bl, u = u0 + ul;
        float pi = gacc[0][bl][ul] + bi[u];
        float pf = gacc[1][bl][ul] + bff[u];
        float pg = gacc[2][bl][ul] + bc[u];
        float po = gacc[3][bl][ul] + bo[u];
        float ig = 1.f / (1.f + __expf(-pi));
        float fg = 1.f / (1.f + __expf(-pf));
        float gg = tanhf(pg);
        float og = 1.f / (1.f + __expf(-po));
        float cold = c_state[(size_t)b * NH + u];
        float cn = fg * cold + ig * gg;
        float hn = og * tanhf(cn);
        c_state[(size_t)b * NH + u] = cn;
        out[((size_t)b * NT + t) * NH + u] = hn;
        hb_out[(size_t)b * NH + u] = f2bf(hn);
        if (hn_out) hn_out[(size_t)b * NH + u] = hn;
    }
}

// ================= launch =================

extern "C" void kernel_launch(void* const* d_in, const int* in_sizes, int n_in,
                              void* d_out, int out_size, void* d_ws, size_t ws_size,
                              hipStream_t stream) {
    const float* x  = (const float*)d_in[0];
    const float* Wi = (const float*)d_in[1];
    const float* Wf = (const float*)d_in[2];
    const float* Wc = (const float*)d_in[3];
    const float* Wo = (const float*)d_in[4];
    const float* Ui = (const float*)d_in[5];
    const float* Uf = (const float*)d_in[6];
    const float* Uc = (const float*)d_in[7];
    const float* Uo = (const float*)d_in[8];
    const float* bi = (const float*)d_in[9];
    const float* bf = (const float*)d_in[10];
    const float* bc = (const float*)d_in[11];
    const float* bo = (const float*)d_in[12];

    float* out = (float*)d_out;
    float* hn  = out + (size_t)NB * NT * NH;
    float* cn  = hn + (size_t)NB * NH;

    // ws layout (fast path): Wb 4MB | xT 32MB | hb 3x128KB | flags 2MB
    const size_t NEED3 = 40239104ULL;
    if (ws_size >= NEED3) {
        char* ws = (char*)d_ws;
        unsigned short* Wb = (unsigned short*)ws;
        unsigned short* xT = (unsigned short*)(ws + 4194304);
        unsigned short* hb = (unsigned short*)(ws + 37748736);
        int* flags         = (int*)(ws + 38141952);
        prep3<<<2048, 256, 0, stream>>>(x, Wi, Wf, Wc, Wo, Wb, xT, flags);
        lstm_persist4<<<NWG, 1024, 0, stream>>>(Ui, Uf, Uc, Uo, bi, bf, bc, bo,
                                                Wb, xT, hb, flags, out, hn, cn);
    } else {
        char* ws = (char*)d_ws;
        unsigned short* Ub  = (unsigned short*)ws;
        unsigned short* Wb  = (unsigned short*)(ws + 8388608);
        unsigned short* hb0 = (unsigned short*)(ws + 12582912);
        unsigned short* hb1 = (unsigned short*)(ws + 12713984);
        float* c_state = cn;
        lstm_prep<<<1024, 256, 0, stream>>>(Ui, Uf, Uc, Uo, Wi, Wf, Wc, Wo,
                                            Ub, Wb, hb0, c_state);
        for (int t = 0; t < NT; t++) {
            unsigned short* hin  = (t & 1) ? hb1 : hb0;
            unsigned short* hout = (t & 1) ? hb0 : hb1;
            lstm_step<<<128, 256, 0, stream>>>(
                x, Ub, Wb, hin, hout, bi, bf, bc, bo,
                out, c_state, (t == NT - 1) ? hn : (float*)nullptr, t);
        }
    }
}

// Round 6
// 7111.072 us; speedup vs baseline: 2.1263x; 2.1263x over previous
//
#include <hip/hip_runtime.h>
#include <hip/hip_bf16.h>

// LSTM B=64, T=512, I=512, H=1024.
// Persistent kernel, 64 WGs x 1024 thr, 1 WG/CU.
// Round-3 structure (proven 6.8ms) + two changes:
//  (1) h loads: 8x pipelined 16B inline-asm sc1 global_load_dwordx4 per thread
//      (128 B/thread, LDS-shared) instead of 16 serialized 8B atomic loads.
//  (2) h-chunk barriers are raw s_barrier + manual lgkmcnt(0) so the counted
//      vmcnt pipeline is NOT drained by __syncthreads' implicit vmcnt(0).
// B2 stays __syncthreads (its vmcnt(0) drain validates absolute vmcnt counts);
// Bf stays __syncthreads (publishes h stores before the flag).

typedef __attribute__((ext_vector_type(8))) short bf16x8;
typedef __attribute__((ext_vector_type(4))) float f32x4;
typedef __attribute__((ext_vector_type(4))) unsigned int u32x4;
typedef unsigned int uint32;
typedef unsigned long long u64;

static __device__ __forceinline__ unsigned short f2bf(float f) {
    union { float f; unsigned int u; } v; v.f = f;
    unsigned int r = v.u + 0x7fffu + ((v.u >> 16) & 1u);  // RNE
    return (unsigned short)(r >> 16);
}

#define NB   64
#define NT   512
#define NI   512
#define NH   1024
#define NWG  64

// ================= fast path =================

__global__ void prep3(const float* __restrict__ x,
                      const float* __restrict__ Wi, const float* __restrict__ Wf,
                      const float* __restrict__ Wc, const float* __restrict__ Wo,
                      unsigned short* __restrict__ Wb, unsigned short* __restrict__ xTb,
                      int* __restrict__ flags)
{
    const int NW = 4 * NH * NI;          // 2097152
    const int NX = NB * NT * NI;         // 16777216
    const int NF = NT * 1024;            // 524288 ints (flag lines, 64B/WG/step)
    const int total = NW + NX + NF;
    for (int idx = blockIdx.x * blockDim.x + threadIdx.x; idx < total;
         idx += gridDim.x * blockDim.x) {
        if (idx < NW) {
            int g = idx >> 19;
            int off = idx & 524287;
            const float* W = (g == 0) ? Wi : (g == 1) ? Wf : (g == 2) ? Wc : Wo;
            Wb[idx] = f2bf(W[off]);
        } else if (idx < NW + NX) {
            int e = idx - NW;
            int b = e >> 18;              // T*I = 262144
            int r = e & 262143;
            int t = r >> 9;
            int i = r & 511;
            xTb[((size_t)t * NB + b) * NI + i] = f2bf(x[e]);
        } else {
            flags[idx - NW - NX] = 0;
        }
    }
}

#define VMWAIT(N)                                                               \
    do { asm volatile("s_waitcnt vmcnt(" #N ")" ::: "memory");                  \
         __builtin_amdgcn_sched_barrier(0); } while (0)

// one 128-k chunk: 4 MFMAs, A from staged LDS, B from U slice in LDS
static __device__ __forceinline__ void chunk_mfma_u(
    f32x4& acc, const unsigned char* sbuf, const unsigned char* Us,
    int abase, int ubase, int kb, int kg, int rm)
{
    #pragma unroll
    for (int kk = 0; kk < 4; ++kk) {
        const int kloc = kk * 32 + kg;
        bf16x8 af = *(const bf16x8*)(sbuf + abase + ((kloc * 2) ^ (rm << 4)));
        bf16x8 bu = *(const bf16x8*)(Us + ubase + (((kb + kloc) * 2) ^ (rm << 4)));
        acc = __builtin_amdgcn_mfma_f32_16x16x32_bf16(af, bu, acc, 0, 0, 0);
    }
}

__global__ __launch_bounds__(1024) void lstm_persist6(
    const float* __restrict__ Ui, const float* __restrict__ Uf,
    const float* __restrict__ Uc, const float* __restrict__ Uo,
    const float* __restrict__ b_i, const float* __restrict__ b_f,
    const float* __restrict__ b_c, const float* __restrict__ b_o,
    const unsigned short* __restrict__ Wb, const unsigned short* __restrict__ xT,
    unsigned short* __restrict__ hb,      // 3 rotating [64][1024] bf16 buffers
    int* __restrict__ flags,              // [NT][64 wg][16 ints] (64B lines)
    float* __restrict__ out, float* __restrict__ hn_arr, float* __restrict__ cn_arr)
{
    __shared__ __align__(16) unsigned char smem[163840];   // exactly 160 KiB
    unsigned char* Us   = smem;                  // 64 rows x 2048B swizzled U slice
    unsigned char* stg0 = smem + 131072;         // 16KB staging buf 0 (aliases gacc)
    unsigned char* stg1 = smem + 147456;         // 16KB staging buf 1
    float* gacc = (float*)(smem + 131072);       // [4][64][16] f32

    const int tid  = threadIdx.x;
    const int lane = tid & 63;
    const int wv   = tid >> 6;      // 0..15
    const int g    = wv & 3;        // gate
    const int mt   = wv >> 2;       // b-tile (16 rows)
    const int rm   = lane & 15;
    const int kg   = (lane >> 4) * 8;
    const int wg   = blockIdx.x;
    const int u0   = wg * 16;

    // ---- prologue: fill U LDS slice (f32 -> bf16, XOR-swizzled rows) ----
    for (int i = 0; i < 8; ++i) {
        int unit = i * 1024 + tid;          // 16B units: 64 rows x 128
        int row  = unit >> 7;
        int k0   = (unit & 127) * 8;
        int gg   = row >> 4;
        const float* src = (gg == 0 ? Ui : gg == 1 ? Uf : gg == 2 ? Uc : Uo)
                           + (size_t)(u0 + (row & 15)) * NH + k0;
        bf16x8 v;
        #pragma unroll
        for (int j = 0; j < 8; ++j) v[j] = (short)f2bf(src[j]);
        *(bf16x8*)(Us + row * 2048 + ((k0 * 2) ^ ((row & 15) << 4))) = v;
    }

    const int bl = tid >> 4, ul = tid & 15;
    const float rbi = b_i[u0 + ul], rbf = b_f[u0 + ul];
    const float rbc = b_c[u0 + ul], rbo = b_o[u0 + ul];
    float creg = 0.f;

    // staging constants: thread stages 16B of row sb, chunk-offset ul*16
    const int sb   = bl;
    const int k8   = ul * 8;
    const int soff = sb * 256 + ((k8 * 2) ^ ((sb & 15) << 4));

    const int abase = (mt * 16 + rm) * 256;
    const int ubase = (g * 16 + rm) * 2048;
    const size_t wrow = ((size_t)(g * NH + u0 + rm)) * NI;
    const unsigned short* wp = Wb + wrow + kg;

    __syncthreads();

    for (int t = 0; t < NT; ++t) {
        f32x4 accx = {0.f, 0.f, 0.f, 0.f};
        f32x4 acc0 = {0.f, 0.f, 0.f, 0.f};
        f32x4 acc1 = {0.f, 0.f, 0.f, 0.f};

        // ===== X part (no h dependency; cached loads; before the flag wait) =====
        {
            const unsigned short* xrow = xT + ((size_t)t * NB + sb) * NI;
            uint4 xr[4];
            #pragma unroll
            for (int c = 0; c < 4; ++c)
                xr[c] = *(const uint4*)(xrow + c * 128 + k8);
            #pragma unroll
            for (int c = 0; c < 4; ++c) {
                unsigned char* dbuf = (c & 1) ? stg1 : stg0;
                *(uint4*)(dbuf + soff) = xr[c];
                __syncthreads();
                #pragma unroll
                for (int kk = 0; kk < 4; ++kk) {
                    const int kloc = kk * 32 + kg;
                    bf16x8 af = *(const bf16x8*)(dbuf + abase + ((kloc * 2) ^ (rm << 4)));
                    bf16x8 bw = *(const bf16x8*)(wp + c * 128 + kk * 32);
                    accx = __builtin_amdgcn_mfma_f32_16x16x32_bf16(af, bw, accx, 0, 0, 0);
                }
            }
        }

        // ===== H part =====
        if (t > 0) {
            // wait for all producers of step t-1 (64 parallel flag-line reads)
            if (wv == 0) {
                const int* fp = flags + (size_t)(t - 1) * 1024 + lane * 16;
                int spins = 0;
                while (__hip_atomic_load(fp, __ATOMIC_RELAXED,
                                         __HIP_MEMORY_SCOPE_AGENT) == 0 &&
                       spins < (1 << 16)) {
                    __builtin_amdgcn_s_sleep(1);
                    ++spins;
                }
            }
            __syncthreads();   // B2: implicit vmcnt(0) -> absolute counts below valid

            // issue 8 pipelined device-coherent loads (128 B/thread total)
            const char* hP = (const char*)hb + ((size_t)((t - 1) % 3) << 17)
                             + ((size_t)sb << 11) + ((size_t)ul << 4);
            u32x4 h0, h1, h2, h3, h4, h5, h6, h7;
            asm volatile(
                "global_load_dwordx4 %0, %8, off offset:0    sc1\n\t"
                "global_load_dwordx4 %1, %8, off offset:256  sc1\n\t"
                "global_load_dwordx4 %2, %8, off offset:512  sc1\n\t"
                "global_load_dwordx4 %3, %8, off offset:768  sc1\n\t"
                "global_load_dwordx4 %4, %8, off offset:1024 sc1\n\t"
                "global_load_dwordx4 %5, %8, off offset:1280 sc1\n\t"
                "global_load_dwordx4 %6, %8, off offset:1536 sc1\n\t"
                "global_load_dwordx4 %7, %8, off offset:1792 sc1"
                : "=v"(h0), "=v"(h1), "=v"(h2), "=v"(h3),
                  "=v"(h4), "=v"(h5), "=v"(h6), "=v"(h7)
                : "v"(hP) : "memory");

            // chunk c: wait load c, stage, RAW barrier (no vmcnt drain), 4 MFMAs
            #define HSTEP(C, HV, WN, ACC)                                        \
                do {                                                              \
                    VMWAIT(WN);                                                   \
                    unsigned char* dbuf_ = ((C) & 1) ? stg1 : stg0;               \
                    *(u32x4*)(dbuf_ + soff) = HV;                                 \
                    asm volatile("s_waitcnt lgkmcnt(0)" ::: "memory");            \
                    __builtin_amdgcn_s_barrier();                                 \
                    __builtin_amdgcn_sched_barrier(0);                            \
                    chunk_mfma_u(ACC, dbuf_, Us, abase, ubase, (C) * 128, kg, rm);\
                } while (0)

            HSTEP(0, h0, 7, acc0);
            HSTEP(1, h1, 6, acc1);
            HSTEP(2, h2, 5, acc0);
            HSTEP(3, h3, 4, acc1);
            HSTEP(4, h4, 3, acc0);
            HSTEP(5, h5, 2, acc1);
            HSTEP(6, h6, 1, acc0);
            HSTEP(7, h7, 0, acc1);
            #undef HSTEP
        }

        // ======= gate exchange (C/D layout: col=lane&15, row=(lane>>4)*4+r) =======
        // gacc aliases stg0: last stg0 read (chunk 6) completed before chunk 7's
        // barrier; chunk 7's reads are stg1 -> safe to overwrite stg0 here.
        #pragma unroll
        for (int r = 0; r < 4; ++r) {
            const int brow = mt * 16 + (lane >> 4) * 4 + r;
            gacc[(g * 64 + brow) * 16 + rm] = accx[r] + acc0[r] + acc1[r];
        }
        __syncthreads();   // B1

        // ======= pointwise: thread owns (b=bl, u=u0+ul); c-state in register =======
        float hn2, cn2;
        {
            float pi = gacc[(0 * 64 + bl) * 16 + ul] + rbi;
            float pf = gacc[(1 * 64 + bl) * 16 + ul] + rbf;
            float pg = gacc[(2 * 64 + bl) * 16 + ul] + rbc;
            float po = gacc[(3 * 64 + bl) * 16 + ul] + rbo;
            float ig  = 1.f / (1.f + __expf(-pi));
            float fg  = 1.f / (1.f + __expf(-pf));
            float gg2 = tanhf(pg);
            float og  = 1.f / (1.f + __expf(-po));
            cn2 = fg * creg + ig * gg2;
            hn2 = og * tanhf(cn2);
            creg = cn2;

            // pack 4 consecutive u into one u64, device-scope store to rotating buf
            unsigned short h16 = f2bf(hn2);
            uint32 lo = (uint32)h16 |
                        ((((uint32)__shfl_down((int)h16, 1, 64)) & 0xffffu) << 16);
            u64 p4 = (u64)lo | ((u64)(uint32)__shfl_down((int)lo, 2, 64) << 32);
            if ((ul & 3) == 0) {
                u64* hd = (u64*)hb + (size_t)(t % 3) * 16384
                          + (size_t)bl * 256 + (size_t)((u0 + ul) >> 2);
                __hip_atomic_store(hd, p4, __ATOMIC_RELAXED,
                                   __HIP_MEMORY_SCOPE_AGENT);
            }
        }

        // Bf: __syncthreads drains h stores (vmcnt(0)); then publish flag
        __syncthreads();
        if (tid == 0)
            __hip_atomic_store(flags + (size_t)t * 1024 + wg * 16, 1,
                               __ATOMIC_RELAXED, __HIP_MEMORY_SCOPE_AGENT);

        // out store after the flag (off the inter-WG critical path)
        out[((size_t)bl * NT + t) * NH + u0 + ul] = hn2;
        if (t == NT - 1) {
            hn_arr[(size_t)bl * NH + u0 + ul] = hn2;
            cn_arr[(size_t)bl * NH + u0 + ul] = cn2;
        }
    }
}

// ================= round-1 fallback (proven) =================

__global__ void lstm_prep(const float* __restrict__ Ui, const float* __restrict__ Uf,
                          const float* __restrict__ Uc, const float* __restrict__ Uo,
                          const float* __restrict__ Wi, const float* __restrict__ Wf,
                          const float* __restrict__ Wc, const float* __restrict__ Wo,
                          unsigned short* __restrict__ Ub, unsigned short* __restrict__ Wb,
                          unsigned short* __restrict__ hb0, float* __restrict__ c_state)
{
    const int NU = 4 * NH * NH;
    const int NW = 4 * NH * NI;
    const int NS = NB * NH;
    const int total = NU + NW + NS + NS;
    for (int idx = blockIdx.x * blockDim.x + threadIdx.x; idx < total;
         idx += gridDim.x * blockDim.x) {
        if (idx < NU) {
            int g = idx >> 20;
            int off = idx & (NH * NH - 1);
            const float* U = (g == 0) ? Ui : (g == 1) ? Uf : (g == 2) ? Uc : Uo;
            Ub[idx] = f2bf(U[off]);
        } else if (idx < NU + NW) {
            int j = idx - NU;
            int g = j >> 19;
            int off = j & (NH * NI - 1);
            const float* W = (g == 0) ? Wi : (g == 1) ? Wf : (g == 2) ? Wc : Wo;
            Wb[j] = f2bf(W[off]);
        } else if (idx < NU + NW + NS) {
            hb0[idx - NU - NW] = 0;
        } else {
            c_state[idx - NU - NW - NS] = 0.0f;
        }
    }
}

__global__ __launch_bounds__(256) void lstm_step(
    const float* __restrict__ x,
    const unsigned short* __restrict__ Ub,
    const unsigned short* __restrict__ Wb,
    const unsigned short* __restrict__ hb_in,
    unsigned short* __restrict__ hb_out,
    const float* __restrict__ bi, const float* __restrict__ bff,
    const float* __restrict__ bc, const float* __restrict__ bo,
    float* __restrict__ out, float* __restrict__ c_state,
    float* __restrict__ hn_out, int t)
{
    __shared__ float gacc[4][32][16];
    const int lane = threadIdx.x & 63;
    const int g    = threadIdx.x >> 6;
    const int u0   = (blockIdx.x >> 1) * 16;
    const int b0   = (blockIdx.x & 1) * 32;
    const int rm   = lane & 15;
    const int kg   = (lane >> 4) * 8;

    f32x4 acc0 = {0.f, 0.f, 0.f, 0.f};
    f32x4 acc1 = {0.f, 0.f, 0.f, 0.f};

    const unsigned short* Ug  = Ub + (size_t)g * (NH * NH) + (size_t)(u0 + rm) * NH;
    const unsigned short* h0p = hb_in + (size_t)(b0 + rm) * NH;
    const unsigned short* h1p = hb_in + (size_t)(b0 + 16 + rm) * NH;
    #pragma unroll 4
    for (int k0 = 0; k0 < NH; k0 += 32) {
        bf16x8 bfrag = *(const bf16x8*)(Ug + k0 + kg);
        bf16x8 a0 = *(const bf16x8*)(h0p + k0 + kg);
        bf16x8 a1 = *(const bf16x8*)(h1p + k0 + kg);
        acc0 = __builtin_amdgcn_mfma_f32_16x16x32_bf16(a0, bfrag, acc0, 0, 0, 0);
        acc1 = __builtin_amdgcn_mfma_f32_16x16x32_bf16(a1, bfrag, acc1, 0, 0, 0);
    }
    const unsigned short* Wg  = Wb + (size_t)g * (NH * NI) + (size_t)(u0 + rm) * NI;
    const float* x0p = x + ((size_t)(b0 + rm) * NT + t) * NI;
    const float* x1p = x + ((size_t)(b0 + 16 + rm) * NT + t) * NI;
    #pragma unroll 2
    for (int k0 = 0; k0 < NI; k0 += 32) {
        bf16x8 bfrag = *(const bf16x8*)(Wg + k0 + kg);
        f32x4 lo0 = *(const f32x4*)(x0p + k0 + kg);
        f32x4 hi0 = *(const f32x4*)(x0p + k0 + kg + 4);
        f32x4 lo1 = *(const f32x4*)(x1p + k0 + kg);
        f32x4 hi1 = *(const f32x4*)(x1p + k0 + kg + 4);
        bf16x8 a0, a1;
        #pragma unroll
        for (int j = 0; j < 4; j++) {
            a0[j]     = (short)f2bf(lo0[j]);
            a0[j + 4] = (short)f2bf(hi0[j]);
            a1[j]     = (short)f2bf(lo1[j]);
            a1[j + 4] = (short)f2bf(hi1[j]);
        }
        acc0 = __builtin_amdgcn_mfma_f32_16x16x32_bf16(a0, bfrag, acc0, 0, 0, 0);
        acc1 = __builtin_amdgcn_mfma_f32_16x16x32_bf16(a1, bfrag, acc1, 0, 0, 0);
    }
    const int row4 = (lane >> 4) * 4;
    #pragma unroll
    for (int r = 0; r < 4; r++) {
        gacc[g][row4 + r][rm]      = acc0[r];
        gacc[g][16 + row4 + r][rm] = acc1[r];
    }
    __syncthreads();
    for (int p = threadIdx.x; p < 512; p += 256) {
        int bl = p >> 4, ul = p & 15;
        int b = b0 + bl, u = u0 + ul;
        float pi = gacc[0][bl][ul] + bi[u];
        float pf = gacc[1][bl][ul] + bff[u];
        float pg = gacc[2][bl][ul] + bc[u];
        float po = gacc[3][bl][ul] + bo[u];
        float ig = 1.f / (1.f + __expf(-pi));
        float fg = 1.f / (1.f + __expf(-pf));
        float gg = tanhf(pg);
        float og = 1.f / (1.f + __expf(-po));
        float cold = c_state[(size_t)b * NH + u];
        float cn = fg * cold + ig * gg;
        float hn = og * tanhf(cn);
        c_state[(size_t)b * NH + u] = cn;
        out[((size_t)b * NT + t) * NH + u] = hn;
        hb_out[(size_t)b * NH + u] = f2bf(hn);
        if (hn_out) hn_out[(size_t)b * NH + u] = hn;
    }
}

// ================= launch =================

extern "C" void kernel_launch(void* const* d_in, const int* in_sizes, int n_in,
                              void* d_out, int out_size, void* d_ws, size_t ws_size,
                              hipStream_t stream) {
    const float* x  = (const float*)d_in[0];
    const float* Wi = (const float*)d_in[1];
    const float* Wf = (const float*)d_in[2];
    const float* Wc = (const float*)d_in[3];
    const float* Wo = (const float*)d_in[4];
    const float* Ui = (const float*)d_in[5];
    const float* Uf = (const float*)d_in[6];
    const float* Uc = (const float*)d_in[7];
    const float* Uo = (const float*)d_in[8];
    const float* bi = (const float*)d_in[9];
    const float* bf = (const float*)d_in[10];
    const float* bc = (const float*)d_in[11];
    const float* bo = (const float*)d_in[12];

    float* out = (float*)d_out;
    float* hn  = out + (size_t)NB * NT * NH;
    float* cn  = hn + (size_t)NB * NH;

    // ws layout (fast path): Wb 4MB | xT 32MB | hb 3x128KB | flags 2MB
    const size_t NEED3 = 40239104ULL;
    if (ws_size >= NEED3) {
        char* ws = (char*)d_ws;
        unsigned short* Wb = (unsigned short*)ws;
        unsigned short* xT = (unsigned short*)(ws + 4194304);
        unsigned short* hb = (unsigned short*)(ws + 37748736);
        int* flags         = (int*)(ws + 38141952);
        prep3<<<2048, 256, 0, stream>>>(x, Wi, Wf, Wc, Wo, Wb, xT, flags);
        lstm_persist6<<<NWG, 1024, 0, stream>>>(Ui, Uf, Uc, Uo, bi, bf, bc, bo,
                                                Wb, xT, hb, flags, out, hn, cn);
    } else {
        char* ws = (char*)d_ws;
        unsigned short* Ub  = (unsigned short*)ws;
        unsigned short* Wb  = (unsigned short*)(ws + 8388608);
        unsigned short* hb0 = (unsigned short*)(ws + 12582912);
        unsigned short* hb1 = (unsigned short*)(ws + 12713984);
        float* c_state = cn;
        lstm_prep<<<1024, 256, 0, stream>>>(Ui, Uf, Uc, Uo, Wi, Wf, Wc, Wo,
                                            Ub, Wb, hb0, c_state);
        for (int t = 0; t < NT; t++) {
            unsigned short* hin  = (t & 1) ? hb1 : hb0;
            unsigned short* hout = (t & 1) ? hb0 : hb1;
            lstm_step<<<128, 256, 0, stream>>>(
                x, Ub, Wb, hin, hout, bi, bf, bc, bo,
                out, c_state, (t == NT - 1) ? hn : (float*)nullptr, t);
        }
    }
}